// Round 2
// baseline (218.525 us; speedup 1.0000x reference)
//
#include <hip/hip_runtime.h>

// Confusion-classification criterion (see reference):
//   pred = argmax(pred_logits[...,0:2])            (tie -> index 0)
//   cls  = g==1 ? (pred ? 1 : 2) : (pred ? 3 : 0)  (TP=1 FN=2 FP=3 TN=0)
//   loss = mean over B*N of -log_softmax(pred_confusion)[cls]
//
// R6 -> R7: fuse the final reduction into the part kernel (ticket pattern).
// R6 post-mortem: fill's WRITE_SIZE drains fully inside its own dispatch
// window -> cache is clean when we run; NT gain was allocate-churn only.
// Remaining controllable cost: the second kernel launch + gap. The last
// block (by device-scope ticket) reduces the 2048 partials with agent-scope
// atomic loads, in R6's exact final-kernel summation order (bitwise-stable).
// Main loop is byte-identical to R6 for clean attribution.

typedef float f32x4 __attribute__((ext_vector_type(4)));
typedef float f32x2 __attribute__((ext_vector_type(2)));

#define NPART   2048
#define K_ELEMS 8

__device__ __forceinline__ float nll_one(f32x4 c, bool gpos, bool pred)
{
    // nll = logsumexp(c) - c[cls]
    float m   = fmaxf(fmaxf(c[0], c[1]), fmaxf(c[2], c[3]));
    float s   = __expf(c[0] - m) + __expf(c[1] - m) +
                __expf(c[2] - m) + __expf(c[3] - m);
    float lse = m + __logf(s);
    // cls: gpos&&pred->1, gpos&&!pred->2, !gpos&&pred->3, else 0
    float xc  = gpos ? (pred ? c[1] : c[2]) : (pred ? c[3] : c[0]);
    return lse - xc;
}

__global__ __launch_bounds__(256) void confusion_fused_kernel(
    const f32x2* __restrict__ lg,    // [total] logit pairs
    const f32x4* __restrict__ conf,  // [total] confusion rows
    const int*   __restrict__ tg,    // [total] targets (int32)
    float* __restrict__ partials,    // [NPART]
    unsigned int* __restrict__ ticket, // memset to 0 before launch
    float* __restrict__ out,
    int total, float inv_total)
{
    const int tid   = threadIdx.x;
    const int chunk = 256 * K_ELEMS;             // 2048 elements per block-pass

    float acc = 0.0f;
    for (int base = blockIdx.x * chunk; base < total;
         base += gridDim.x * chunk) {

        if (base + chunk <= total) {
            // full tile: issue all coalesced non-allocating loads first
            f32x4 c[K_ELEMS];
            f32x2 l[K_ELEMS];
            int   g[K_ELEMS];
            #pragma unroll
            for (int k = 0; k < K_ELEMS; ++k) {
                int e = base + k * 256 + tid;    // unit stride per instruction
                c[k] = __builtin_nontemporal_load(conf + e);
                l[k] = __builtin_nontemporal_load(lg + e);
                g[k] = __builtin_nontemporal_load(tg + e);
            }
            #pragma unroll
            for (int k = 0; k < K_ELEMS; ++k)
                acc += nll_one(c[k], g[k] == 1, l[k][1] > l[k][0]);
        } else {
            // ragged tail tile (not hit at B*N = 4,194,304: 2048*2048 exact)
            for (int k = 0; k < K_ELEMS; ++k) {
                int e = base + k * 256 + tid;
                if (e < total) {
                    f32x2 lv = __builtin_nontemporal_load(lg + e);
                    f32x4 cv = __builtin_nontemporal_load(conf + e);
                    int   gv = __builtin_nontemporal_load(tg + e);
                    acc += nll_one(cv, gv == 1, lv[1] > lv[0]);
                }
            }
        }
    }

    // wave-64 reduce
    #pragma unroll
    for (int off = 32; off > 0; off >>= 1)
        acc += __shfl_down(acc, off, 64);

    __shared__ float wsum[4];
    __shared__ int   islast;
    const int lane = tid & 63;
    const int wid  = tid >> 6;
    if (lane == 0) wsum[wid] = acc;
    __syncthreads();

    if (tid == 0) {
        float bsum = wsum[0] + wsum[1] + wsum[2] + wsum[3];
        // release the partial to agent scope, then take a ticket
        __hip_atomic_store(partials + blockIdx.x, bsum,
                           __ATOMIC_RELEASE, __HIP_MEMORY_SCOPE_AGENT);
        unsigned int old = atomicAdd(ticket, 1u);  // device-scope
        islast = (old == gridDim.x - 1) ? 1 : 0;
    }
    __syncthreads();

    if (islast) {
        // last block: reduce partials in R6's exact final-kernel order.
        // Agent-scope atomic loads read from the coherence point (no stale
        // per-XCD L2 lines).
        float f = 0.0f;
        const int nquads = NPART / 4;
        for (int i = tid; i < nquads; i += 256) {
            float p0 = __hip_atomic_load(partials + 4 * i + 0,
                          __ATOMIC_RELAXED, __HIP_MEMORY_SCOPE_AGENT);
            float p1 = __hip_atomic_load(partials + 4 * i + 1,
                          __ATOMIC_RELAXED, __HIP_MEMORY_SCOPE_AGENT);
            float p2 = __hip_atomic_load(partials + 4 * i + 2,
                          __ATOMIC_RELAXED, __HIP_MEMORY_SCOPE_AGENT);
            float p3 = __hip_atomic_load(partials + 4 * i + 3,
                          __ATOMIC_RELAXED, __HIP_MEMORY_SCOPE_AGENT);
            f += (p0 + p1) + (p2 + p3);
        }
        #pragma unroll
        for (int off = 32; off > 0; off >>= 1)
            f += __shfl_down(f, off, 64);

        __shared__ float fsum[4];
        if (lane == 0) fsum[wid] = f;
        __syncthreads();
        if (tid == 0)
            out[0] = (fsum[0] + fsum[1] + fsum[2] + fsum[3]) * inv_total;
    }
}

extern "C" void kernel_launch(void* const* d_in, const int* in_sizes, int n_in,
                              void* d_out, int out_size, void* d_ws, size_t ws_size,
                              hipStream_t stream)
{
    const f32x2* lg    = (const f32x2*)d_in[0];
    const f32x4* conf  = (const f32x4*)d_in[1];
    const int*   tg    = (const int*)d_in[2];
    float*       out   = (float*)d_out;
    float*       parts = (float*)d_ws;        // NPART floats (8 KB)
    unsigned int* ticket = (unsigned int*)((char*)d_ws + NPART * sizeof(float));

    const int total = in_sizes[2];            // B*N = 4,194,304

    // zero the ticket each iteration (workspace is poisoned by the harness);
    // a 4-byte memset node is graph-capturable (same class as the harness's
    // own reset memsets / the allowed hipMemcpyAsync).
    hipMemsetAsync(ticket, 0, sizeof(unsigned int), stream);

    confusion_fused_kernel<<<NPART, 256, 0, stream>>>(
        lg, conf, tg, parts, ticket, out, total, 1.0f / (float)total);
}

// Round 3
// 143.553 us; speedup vs baseline: 1.5223x; 1.5223x over previous
//
#include <hip/hip_runtime.h>

// Confusion-classification criterion (see reference):
//   pred = argmax(pred_logits[...,0:2])            (tie -> index 0)
//   cls  = g==1 ? (pred ? 1 : 2) : (pred ? 3 : 0)  (TP=1 FN=2 FP=3 TN=0)
//   loss = mean over B*N of -log_softmax(pred_confusion)[cls]
//
// R7 -> R8: keep the single-kernel fusion but remove the per-block
// agent-scope RELEASE fence. R7 post-mortem: dur was a fixed 111.6 us
// independent of memory traffic (warm replays identical) -> the 2048
// buffer_wbl2 L2-writebacks emitted by __hip_atomic_store(RELEASE, AGENT)
// serialized at the TCCs. Fix: relaxed agent-scope atomic store (bypasses
// L2 to the memory-side coherence point, no cache maintenance) + a
// thread-local s_waitcnt vmcnt(0) before the relaxed ticket RMW. Reader
// side was already relaxed agent loads. Main loop byte-identical to R6/R7.

typedef float f32x4 __attribute__((ext_vector_type(4)));
typedef float f32x2 __attribute__((ext_vector_type(2)));

#define NPART   2048
#define K_ELEMS 8

__device__ __forceinline__ float nll_one(f32x4 c, bool gpos, bool pred)
{
    // nll = logsumexp(c) - c[cls]
    float m   = fmaxf(fmaxf(c[0], c[1]), fmaxf(c[2], c[3]));
    float s   = __expf(c[0] - m) + __expf(c[1] - m) +
                __expf(c[2] - m) + __expf(c[3] - m);
    float lse = m + __logf(s);
    // cls: gpos&&pred->1, gpos&&!pred->2, !gpos&&pred->3, else 0
    float xc  = gpos ? (pred ? c[1] : c[2]) : (pred ? c[3] : c[0]);
    return lse - xc;
}

__global__ __launch_bounds__(256) void confusion_fused_kernel(
    const f32x2* __restrict__ lg,    // [total] logit pairs
    const f32x4* __restrict__ conf,  // [total] confusion rows
    const int*   __restrict__ tg,    // [total] targets (int32)
    float* __restrict__ partials,    // [NPART]
    unsigned int* __restrict__ ticket, // memset to 0 before launch
    float* __restrict__ out,
    int total, float inv_total)
{
    const int tid   = threadIdx.x;
    const int chunk = 256 * K_ELEMS;             // 2048 elements per block-pass

    float acc = 0.0f;
    for (int base = blockIdx.x * chunk; base < total;
         base += gridDim.x * chunk) {

        if (base + chunk <= total) {
            // full tile: issue all coalesced non-allocating loads first
            f32x4 c[K_ELEMS];
            f32x2 l[K_ELEMS];
            int   g[K_ELEMS];
            #pragma unroll
            for (int k = 0; k < K_ELEMS; ++k) {
                int e = base + k * 256 + tid;    // unit stride per instruction
                c[k] = __builtin_nontemporal_load(conf + e);
                l[k] = __builtin_nontemporal_load(lg + e);
                g[k] = __builtin_nontemporal_load(tg + e);
            }
            #pragma unroll
            for (int k = 0; k < K_ELEMS; ++k)
                acc += nll_one(c[k], g[k] == 1, l[k][1] > l[k][0]);
        } else {
            // ragged tail tile (not hit at B*N = 4,194,304: 2048*2048 exact)
            for (int k = 0; k < K_ELEMS; ++k) {
                int e = base + k * 256 + tid;
                if (e < total) {
                    f32x2 lv = __builtin_nontemporal_load(lg + e);
                    f32x4 cv = __builtin_nontemporal_load(conf + e);
                    int   gv = __builtin_nontemporal_load(tg + e);
                    acc += nll_one(cv, gv == 1, lv[1] > lv[0]);
                }
            }
        }
    }

    // wave-64 reduce
    #pragma unroll
    for (int off = 32; off > 0; off >>= 1)
        acc += __shfl_down(acc, off, 64);

    __shared__ float wsum[4];
    __shared__ int   islast;
    const int lane = tid & 63;
    const int wid  = tid >> 6;
    if (lane == 0) wsum[wid] = acc;
    __syncthreads();

    if (tid == 0) {
        float bsum = wsum[0] + wsum[1] + wsum[2] + wsum[3];
        // RELAXED agent-scope atomic store: goes straight to the
        // memory-side coherence point (no buffer_wbl2 fence).
        __hip_atomic_store(partials + blockIdx.x, bsum,
                           __ATOMIC_RELAXED, __HIP_MEMORY_SCOPE_AGENT);
        // order: partial must reach the coherence point before the ticket
        // RMW. vmcnt(0) retires the sc1 write; "memory" stops reordering.
        asm volatile("s_waitcnt vmcnt(0)" ::: "memory");
        unsigned int old = __hip_atomic_fetch_add(
            ticket, 1u, __ATOMIC_RELAXED, __HIP_MEMORY_SCOPE_AGENT);
        islast = (old == gridDim.x - 1) ? 1 : 0;
    }
    __syncthreads();

    if (islast) {
        // last block: reduce partials in R6's exact final-kernel order
        // (bitwise-stable). Relaxed agent-scope loads read the coherence
        // point directly (no stale per-XCD L2 lines, no buffer_inv).
        float f = 0.0f;
        const int nquads = NPART / 4;
        for (int i = tid; i < nquads; i += 256) {
            float p0 = __hip_atomic_load(partials + 4 * i + 0,
                          __ATOMIC_RELAXED, __HIP_MEMORY_SCOPE_AGENT);
            float p1 = __hip_atomic_load(partials + 4 * i + 1,
                          __ATOMIC_RELAXED, __HIP_MEMORY_SCOPE_AGENT);
            float p2 = __hip_atomic_load(partials + 4 * i + 2,
                          __ATOMIC_RELAXED, __HIP_MEMORY_SCOPE_AGENT);
            float p3 = __hip_atomic_load(partials + 4 * i + 3,
                          __ATOMIC_RELAXED, __HIP_MEMORY_SCOPE_AGENT);
            f += (p0 + p1) + (p2 + p3);
        }
        #pragma unroll
        for (int off = 32; off > 0; off >>= 1)
            f += __shfl_down(f, off, 64);

        __shared__ float fsum[4];
        if (lane == 0) fsum[wid] = f;
        __syncthreads();
        if (tid == 0)
            out[0] = (fsum[0] + fsum[1] + fsum[2] + fsum[3]) * inv_total;
    }
}

extern "C" void kernel_launch(void* const* d_in, const int* in_sizes, int n_in,
                              void* d_out, int out_size, void* d_ws, size_t ws_size,
                              hipStream_t stream)
{
    const f32x2* lg    = (const f32x2*)d_in[0];
    const f32x4* conf  = (const f32x4*)d_in[1];
    const int*   tg    = (const int*)d_in[2];
    float*       out   = (float*)d_out;
    float*       parts = (float*)d_ws;        // NPART floats (8 KB)
    unsigned int* ticket = (unsigned int*)((char*)d_ws + NPART * sizeof(float));

    const int total = in_sizes[2];            // B*N = 4,194,304

    // zero the ticket each iteration (workspace is poisoned by the harness);
    // a 4-byte memset node is graph-capturable.
    hipMemsetAsync(ticket, 0, sizeof(unsigned int), stream);

    confusion_fused_kernel<<<NPART, 256, 0, stream>>>(
        lg, conf, tg, parts, ticket, out, total, 1.0f / (float)total);
}

// Round 4
// 129.514 us; speedup vs baseline: 1.6873x; 1.1084x over previous
//
#include <hip/hip_runtime.h>

// Confusion-classification criterion (see reference):
//   pred = argmax(pred_logits[...,0:2])            (tie -> index 0)
//   cls  = g==1 ? (pred ? 1 : 2) : (pred ? 3 : 0)  (TP=1 FN=2 FP=3 TN=0)
//   loss = mean over B*N of -log_softmax(pred_confusion)[cls]
//
// R8 -> R9: REVERT to the measured-best R6 two-kernel structure (129.2 us).
// Fusion post-mortems: (R7) per-block agent-scope RELEASE emitted 2048
// buffer_wbl2 L2-writebacks -> fixed 111.6 us serialization; (R8) even with
// relaxed coherence-point atomics, the 2048 same-line ticket RMWs bunch at
// the uniform kernel tail and serialize (+14.4 us vs R6). A separate 3 us
// final kernel + ~2 us launch gap is cheaper than any same-kernel cross-XCD
// handoff on this part. Main loop: single exact pass, NT (non-allocating)
// unit-stride loads, K=8, 2048 blocks x 256 threads.

typedef float f32x4 __attribute__((ext_vector_type(4)));
typedef float f32x2 __attribute__((ext_vector_type(2)));

#define NPART   2048
#define K_ELEMS 8

__device__ __forceinline__ float nll_one(f32x4 c, bool gpos, bool pred)
{
    // nll = logsumexp(c) - c[cls]
    float m   = fmaxf(fmaxf(c[0], c[1]), fmaxf(c[2], c[3]));
    float s   = __expf(c[0] - m) + __expf(c[1] - m) +
                __expf(c[2] - m) + __expf(c[3] - m);
    float lse = m + __logf(s);
    // cls: gpos&&pred->1, gpos&&!pred->2, !gpos&&pred->3, else 0
    float xc  = gpos ? (pred ? c[1] : c[2]) : (pred ? c[3] : c[0]);
    return lse - xc;
}

__global__ __launch_bounds__(256) void confusion_part_kernel(
    const f32x2* __restrict__ lg,    // [total] logit pairs
    const f32x4* __restrict__ conf,  // [total] confusion rows
    const int*   __restrict__ tg,    // [total] targets (int32)
    float* __restrict__ partials,    // [NPART]
    int total)
{
    const int tid   = threadIdx.x;
    const int chunk = 256 * K_ELEMS;             // 2048 elements per block-pass

    float acc = 0.0f;
    for (int base = blockIdx.x * chunk; base < total;
         base += gridDim.x * chunk) {

        if (base + chunk <= total) {
            // full tile: issue all coalesced non-allocating loads first
            f32x4 c[K_ELEMS];
            f32x2 l[K_ELEMS];
            int   g[K_ELEMS];
            #pragma unroll
            for (int k = 0; k < K_ELEMS; ++k) {
                int e = base + k * 256 + tid;    // unit stride per instruction
                c[k] = __builtin_nontemporal_load(conf + e);
                l[k] = __builtin_nontemporal_load(lg + e);
                g[k] = __builtin_nontemporal_load(tg + e);
            }
            #pragma unroll
            for (int k = 0; k < K_ELEMS; ++k)
                acc += nll_one(c[k], g[k] == 1, l[k][1] > l[k][0]);
        } else {
            // ragged tail tile (not hit at B*N = 4,194,304: 2048*2048 exact)
            for (int k = 0; k < K_ELEMS; ++k) {
                int e = base + k * 256 + tid;
                if (e < total) {
                    f32x2 lv = __builtin_nontemporal_load(lg + e);
                    f32x4 cv = __builtin_nontemporal_load(conf + e);
                    int   gv = __builtin_nontemporal_load(tg + e);
                    acc += nll_one(cv, gv == 1, lv[1] > lv[0]);
                }
            }
        }
    }

    // wave-64 reduce
    #pragma unroll
    for (int off = 32; off > 0; off >>= 1)
        acc += __shfl_down(acc, off, 64);

    __shared__ float wsum[4];
    int lane = tid & 63;
    int wid  = tid >> 6;
    if (lane == 0) wsum[wid] = acc;
    __syncthreads();

    if (tid == 0)
        partials[blockIdx.x] = wsum[0] + wsum[1] + wsum[2] + wsum[3];
}

__global__ __launch_bounds__(256) void confusion_final_kernel(
    const f32x4* __restrict__ partials, float* __restrict__ out,
    int nquads, float inv_total)
{
    float acc = 0.0f;
    for (int i = threadIdx.x; i < nquads; i += 256) {
        f32x4 p = partials[i];
        acc += (p[0] + p[1]) + (p[2] + p[3]);
    }

    #pragma unroll
    for (int off = 32; off > 0; off >>= 1)
        acc += __shfl_down(acc, off, 64);

    __shared__ float wsum[4];
    int lane = threadIdx.x & 63;
    int wid  = threadIdx.x >> 6;
    if (lane == 0) wsum[wid] = acc;
    __syncthreads();

    if (threadIdx.x == 0)
        out[0] = (wsum[0] + wsum[1] + wsum[2] + wsum[3]) * inv_total;
}

extern "C" void kernel_launch(void* const* d_in, const int* in_sizes, int n_in,
                              void* d_out, int out_size, void* d_ws, size_t ws_size,
                              hipStream_t stream)
{
    const f32x2* lg    = (const f32x2*)d_in[0];
    const f32x4* conf  = (const f32x4*)d_in[1];
    const int*   tg    = (const int*)d_in[2];
    float*       out   = (float*)d_out;
    float*       parts = (float*)d_ws;        // NPART floats (8 KB)

    const int total = in_sizes[2];            // B*N = 4,194,304

    confusion_part_kernel<<<NPART, 256, 0, stream>>>(
        lg, conf, tg, parts, total);
    confusion_final_kernel<<<1, 256, 0, stream>>>(
        (const f32x4*)parts, out, NPART / 4, 1.0f / (float)total);
}